// Round 1
// baseline (143.029 us; speedup 1.0000x reference)
//
#include <hip/hip_runtime.h>
#include <math.h>

#define BB 32
#define SS 4096
#define DD 1024
#define NCHUNK 16
#define CS (SS / NCHUNK)   // 256 source positions per chunk block

// ---------------------------------------------------------------------------
// Kernel 1: q_proj[b][d] = sum_k query[b][k] * Wa[k][d] + bias[d]
// grid (D/64, B), 64 threads (1 wave). Query row staged in LDS; Wa column
// loads are coalesced 256B per wave; 4 rotating accumulators hide FMA latency.
// ---------------------------------------------------------------------------
__global__ __launch_bounds__(64) void qproj_kernel(
    const float* __restrict__ query, const float* __restrict__ Wa,
    const float* __restrict__ bias, float* __restrict__ qproj)
{
    const int tid = threadIdx.x;           // 0..63
    const int d   = blockIdx.x * 64 + tid;
    const int b   = blockIdx.y;

    __shared__ float qlds[DD];
    {
        const float4* qsrc = (const float4*)(query + (size_t)b * DD);
        float4* qdst = (float4*)qlds;
        #pragma unroll
        for (int j = 0; j < 4; ++j) qdst[tid + 64 * j] = qsrc[tid + 64 * j];
    }
    __syncthreads();

    const float* wp = Wa + d;
    float ac0 = 0.f, ac1 = 0.f, ac2 = 0.f, ac3 = 0.f;
    for (int k = 0; k < DD; k += 8) {
        float w0 = wp[(k + 0) * DD], w1 = wp[(k + 1) * DD];
        float w2 = wp[(k + 2) * DD], w3 = wp[(k + 3) * DD];
        float w4 = wp[(k + 4) * DD], w5 = wp[(k + 5) * DD];
        float w6 = wp[(k + 6) * DD], w7 = wp[(k + 7) * DD];
        ac0 += qlds[k + 0] * w0;  ac1 += qlds[k + 1] * w1;
        ac2 += qlds[k + 2] * w2;  ac3 += qlds[k + 3] * w3;
        ac0 += qlds[k + 4] * w4;  ac1 += qlds[k + 5] * w5;
        ac2 += qlds[k + 6] * w6;  ac3 += qlds[k + 7] * w7;
    }
    qproj[(size_t)b * DD + d] = (ac0 + ac1) + (ac2 + ac3) + bias[d];
}

// ---------------------------------------------------------------------------
// Kernel 2: per-(b, chunk) online-softmax partial.
// 4 waves/block; each wave iterates over its s-rows: coalesced float4 loads of
// values[b,s,:] (kept in registers), dot with register-resident q stripe,
// wave shuffle-reduce -> score, online (m,l,acc) update. Then block-combine
// the 4 wave partials in LDS and emit one (m,l,ctx[1024]) partial per block.
// ---------------------------------------------------------------------------
__global__ __launch_bounds__(256) void attn_partial_kernel(
    const float* __restrict__ values, const float* __restrict__ qproj,
    float* __restrict__ scores, float* __restrict__ pm,
    float* __restrict__ pl, float* __restrict__ pctx)
{
    const int chunk = blockIdx.x;
    const int b     = blockIdx.y;
    const int tid   = threadIdx.x;
    const int lane  = tid & 63;
    const int wave  = tid >> 6;

    // q stripe in registers: lane covers d = {lane*4..}, {256+lane*4..}, ...
    const float4* qp = (const float4*)(qproj + (size_t)b * DD);
    const float4 q0 = qp[lane], q1 = qp[64 + lane], q2 = qp[128 + lane], q3 = qp[192 + lane];

    float m = -INFINITY, l = 0.f;
    float4 a0 = make_float4(0,0,0,0), a1 = a0, a2 = a0, a3 = a0;

    const size_t vbase = ((size_t)b * SS + (size_t)chunk * CS) * DD;

    for (int i = wave; i < CS; i += 4) {
        const float4* vp = (const float4*)(values + vbase + (size_t)i * DD);
        const float4 v0 = vp[lane], v1 = vp[64 + lane], v2 = vp[128 + lane], v3 = vp[192 + lane];

        float part = v0.x*q0.x + v0.y*q0.y + v0.z*q0.z + v0.w*q0.w
                   + v1.x*q1.x + v1.y*q1.y + v1.z*q1.z + v1.w*q1.w
                   + v2.x*q2.x + v2.y*q2.y + v2.z*q2.z + v2.w*q2.w
                   + v3.x*q3.x + v3.y*q3.y + v3.z*q3.z + v3.w*q3.w;
        #pragma unroll
        for (int off = 32; off; off >>= 1) part += __shfl_xor(part, off, 64);

        if (lane == 0) scores[(size_t)b * SS + (size_t)chunk * CS + i] = part;

        const float mn = fmaxf(m, part);
        const float sc = __expf(m - mn);     // m=-inf first iter -> 0
        const float p  = __expf(part - mn);
        l = l * sc + p;
        a0.x = a0.x*sc + p*v0.x;  a0.y = a0.y*sc + p*v0.y;  a0.z = a0.z*sc + p*v0.z;  a0.w = a0.w*sc + p*v0.w;
        a1.x = a1.x*sc + p*v1.x;  a1.y = a1.y*sc + p*v1.y;  a1.z = a1.z*sc + p*v1.z;  a1.w = a1.w*sc + p*v1.w;
        a2.x = a2.x*sc + p*v2.x;  a2.y = a2.y*sc + p*v2.y;  a2.z = a2.z*sc + p*v2.z;  a2.w = a2.w*sc + p*v2.w;
        a3.x = a3.x*sc + p*v3.x;  a3.y = a3.y*sc + p*v3.y;  a3.z = a3.z*sc + p*v3.z;  a3.w = a3.w*sc + p*v3.w;
        m = mn;
    }

    // ---- block combine of the 4 wave partials ----
    __shared__ float  smx[4], slx[4];
    __shared__ float4 sacc[4][256];
    sacc[wave][lane]       = a0;
    sacc[wave][64 + lane]  = a1;
    sacc[wave][128 + lane] = a2;
    sacc[wave][192 + lane] = a3;
    if (lane == 0) { smx[wave] = m; slx[wave] = l; }
    __syncthreads();

    const float mb = fmaxf(fmaxf(smx[0], smx[1]), fmaxf(smx[2], smx[3]));
    const float c0 = __expf(smx[0] - mb), c1 = __expf(smx[1] - mb);
    const float c2 = __expf(smx[2] - mb), c3 = __expf(smx[3] - mb);
    const float lb = c0*slx[0] + c1*slx[1] + c2*slx[2] + c3*slx[3];

    const float4 t0 = sacc[0][tid], t1 = sacc[1][tid], t2 = sacc[2][tid], t3 = sacc[3][tid];
    float4 r;
    r.x = c0*t0.x + c1*t1.x + c2*t2.x + c3*t3.x;
    r.y = c0*t0.y + c1*t1.y + c2*t2.y + c3*t3.y;
    r.z = c0*t0.z + c1*t1.z + c2*t2.z + c3*t3.z;
    r.w = c0*t0.w + c1*t1.w + c2*t2.w + c3*t3.w;
    ((float4*)pctx)[((size_t)b * NCHUNK + chunk) * 256 + tid] = r;
    if (tid == 0) {
        pm[b * NCHUNK + chunk] = mb;
        pl[b * NCHUNK + chunk] = lb;
    }
}

// ---------------------------------------------------------------------------
// Kernel 3: exact recombination across the 16 chunk partials, then write
// context and attention weights. One block per b.
// ---------------------------------------------------------------------------
__global__ __launch_bounds__(256) void attn_finalize_kernel(
    const float* __restrict__ pm, const float* __restrict__ pl,
    const float* __restrict__ pctx, const float* __restrict__ scores,
    float* __restrict__ out)
{
    const int b   = blockIdx.x;
    const int tid = threadIdx.x;

    float M = -INFINITY;
    #pragma unroll
    for (int c = 0; c < NCHUNK; ++c) M = fmaxf(M, pm[b * NCHUNK + c]);

    float coef[NCHUNK];
    float L = 0.f;
    #pragma unroll
    for (int c = 0; c < NCHUNK; ++c) {
        coef[c] = __expf(pm[b * NCHUNK + c] - M);
        L += coef[c] * pl[b * NCHUNK + c];
    }
    const float invL = 1.0f / L;

    // context: each thread owns one float4 of the 1024-wide row
    {
        const float4* pc = (const float4*)pctx + (size_t)b * NCHUNK * 256;
        float4 acc = make_float4(0,0,0,0);
        #pragma unroll
        for (int c = 0; c < NCHUNK; ++c) {
            const float4 t = pc[(size_t)c * 256 + tid];
            acc.x += coef[c] * t.x;  acc.y += coef[c] * t.y;
            acc.z += coef[c] * t.z;  acc.w += coef[c] * t.w;
        }
        float4 r;
        r.x = acc.x * invL; r.y = acc.y * invL; r.z = acc.z * invL; r.w = acc.w * invL;
        ((float4*)out)[(size_t)b * 256 + tid] = r;
    }

    // weights
    float* wout = out + (size_t)BB * DD;
    const float* sc = scores + (size_t)b * SS;
    for (int s = tid; s < SS; s += 256) {
        wout[(size_t)b * SS + s] = __expf(sc[s] - M) * invL;
    }
}

extern "C" void kernel_launch(void* const* d_in, const int* in_sizes, int n_in,
                              void* d_out, int out_size, void* d_ws, size_t ws_size,
                              hipStream_t stream) {
    const float* query  = (const float*)d_in[0];
    const float* values = (const float*)d_in[1];
    const float* Wa     = (const float*)d_in[2];
    const float* bias   = (const float*)d_in[3];
    float* out = (float*)d_out;

    char* ws = (char*)d_ws;
    float* qproj  = (float*)(ws);                 // 32*1024*4      = 131072 B
    float* scores = (float*)(ws + 131072);        // 32*4096*4     = 524288 B
    float* pm     = (float*)(ws + 655360);        // 512*4         =   2048 B
    float* pl     = (float*)(ws + 657408);        // 512*4         =   2048 B
    float* pctx   = (float*)(ws + 659456);        // 512*1024*4    = 2 MiB   (16B aligned)

    dim3 g1(DD / 64, BB);
    qproj_kernel<<<g1, 64, 0, stream>>>(query, Wa, bias, qproj);

    dim3 g2(NCHUNK, BB);
    attn_partial_kernel<<<g2, 256, 0, stream>>>(values, qproj, scores, pm, pl, pctx);

    attn_finalize_kernel<<<BB, 256, 0, stream>>>(pm, pl, pctx, scores, out);
}